// Round 10
// baseline (2023.567 us; speedup 1.0000x reference)
//
#include <hip/hip_runtime.h>
#include <hip/hip_cooperative_groups.h>
#include <math.h>

namespace cg = cooperative_groups;

#define NND 65536   // total nodes
#define NPER 512    // nodes per graph
#define NGR 128     // graphs (B)
#define DD 128      // feature dim
#define NED 524288  // edges
#define NBLK 512    // cooperative grid
#define TPB 256

typedef __attribute__((ext_vector_type(8))) short short8;
typedef __attribute__((ext_vector_type(4))) float f32x4;

__device__ __forceinline__ unsigned short f2b(float f) {
  unsigned u = __float_as_uint(f);
  return (unsigned short)((u + 0x7FFFu + ((u >> 16) & 1u)) >> 16);
}
__device__ __forceinline__ float b2f(unsigned short h) {
  return __uint_as_float(((unsigned)h) << 16);
}

// ---------------- shared memory (hoisted so device funcs share one block) ----
struct SharedMem {
  short Ah[2048];
  short Al[2048];
  float s_sp[4][64];
  float s_sc[NPER];
  float s_t[128];
  unsigned char s_sel[128];
  int s_rk[256];
  float4 red4[512];
  float s_norm;
  int s_tmp[128];
  int s_excl[128];
  int s_b[512];
  float z[256];
  float h1[128];
  float h2[64];
};  // ~26 KB

// ---------------- device bodies (shared by mega kernel and fallback) --------

__device__ __forceinline__ void prepw_elem(int e, const float* wl0, const float* wr0,
                                           const float* wl1, const float* wr1,
                                           const float* wl2, const float* wr2,
                                           unsigned short* Whi, unsigned short* Wlo) {
  const float* wls[3] = {wl0, wl1, wl2};
  const float* wrs[3] = {wr0, wr1, wr2};
  int l = e >> 15;
  int o = e & 32767;
  int j = o & 7;
  int lane = (o >> 3) & 63;
  int nt = (o >> 9) & 7;
  int kc = o >> 12;
  int li = lane & 15, q = lane >> 4;
  int n = nt * 16 + li;
  int k = kc * 32 + q * 8 + j;
  const float* src = (k < 128) ? wls[l] : wrs[l];
  float v = src[n * DD + (k & 127)];
  unsigned short hi = f2b(v);
  Whi[e] = hi;
  Wlo[e] = f2b(v - b2f(hi));
}

// aggregate 4 consecutive dsts (one wave), masked path (layer0 tm == {1,1})
__device__ __forceinline__ void agg_group4(const int d0, const float* __restrict__ x,
                                           const float2* __restrict__ tm,
                                           const int* __restrict__ off,
                                           const int* __restrict__ ssrc,
                                           unsigned short* __restrict__ mhi,
                                           unsigned short* __restrict__ mlo,
                                           const int lane) {
  const int half = lane >> 5;
  const int l = lane & 31;
  int offv = 0;
  if (lane < 5) offv = off[d0 + lane];
  float deadv = 1.f;
  if (lane < 4) deadv = tm[d0 + lane].x;
  const int b0 = __shfl(offv, 0);
  const int b1 = __shfl(offv, 1);
  const int b2 = __shfl(offv, 2);
  const int b3 = __shfl(offv, 3);
  const int e3 = __shfl(offv, 4);
  const float dds[4] = {__shfl(deadv, 0), __shfl(deadv, 1), __shfl(deadv, 2), __shfl(deadv, 3)};
  const int begs[4] = {b0, b1, b2, b3};
  const int ends[4] = {b1, b2, b3, e3};

  float4 acc[4];
  int deg[4];
#pragma unroll
  for (int d = 0; d < 4; ++d) {
    acc[d] = make_float4(0.f, 0.f, 0.f, 0.f);
    deg[d] = 0;
  }

  for (int base = b0; base < e3; base += 64) {
    const int nwin = min(64, e3 - base);
    int sv = 0;
    float tv = 0.f;
    int live = 0;
    if (lane < nwin) {
      sv = ssrc[base + lane];
      const float2 mt = tm[sv];
      live = (mt.x != 0.f);
      tv = mt.y;
    }
    const unsigned long long bl = __ballot(live);

#pragma unroll
    for (int d = 0; d < 4; ++d) {
      if (dds[d] == 0.f) continue;
      const int lo = max(begs[d], base);
      const int hi = min(ends[d], base + 64);
      if (lo >= hi) continue;
      const int j0 = lo - base;
      const int j1 = hi - base;
      const unsigned long long wm =
          (((j1 == 64) ? ~0ull : ((1ull << j1) - 1)) & ~((1ull << j0) - 1));
      deg[d] += (int)__popcll(bl & wm);
      int j = j0 + half;
      for (; j + 6 < j1; j += 8) {
        const int s0 = __shfl(sv, j);
        const int s1 = __shfl(sv, j + 2);
        const int s2 = __shfl(sv, j + 4);
        const int s3 = __shfl(sv, j + 6);
        const float4 v0 = *(const float4*)(x + (size_t)s0 * DD + l * 4);
        const float4 v1 = *(const float4*)(x + (size_t)s1 * DD + l * 4);
        const float4 v2 = *(const float4*)(x + (size_t)s2 * DD + l * 4);
        const float4 v3 = *(const float4*)(x + (size_t)s3 * DD + l * 4);
        const float t0 = __shfl(tv, j), t1 = __shfl(tv, j + 2);
        const float t2 = __shfl(tv, j + 4), t3 = __shfl(tv, j + 6);
        acc[d].x += v0.x * t0 + v1.x * t1 + v2.x * t2 + v3.x * t3;
        acc[d].y += v0.y * t0 + v1.y * t1 + v2.y * t2 + v3.y * t3;
        acc[d].z += v0.z * t0 + v1.z * t1 + v2.z * t2 + v3.z * t3;
        acc[d].w += v0.w * t0 + v1.w * t1 + v2.w * t2 + v3.w * t3;
      }
      for (; j < j1; j += 2) {
        const int s = __shfl(sv, j);
        const float4 v = *(const float4*)(x + (size_t)s * DD + l * 4);
        const float t = __shfl(tv, j);
        acc[d].x += v.x * t;
        acc[d].y += v.y * t;
        acc[d].z += v.z * t;
        acc[d].w += v.w * t;
      }
    }
  }

#pragma unroll
  for (int d = 0; d < 4; ++d) {
    float4 a = acc[d];
    a.x += __shfl(a.x, lane ^ 32);
    a.y += __shfl(a.y, lane ^ 32);
    a.z += __shfl(a.z, lane ^ 32);
    a.w += __shfl(a.w, lane ^ 32);
    if (lane < 32) {
      const float inv = (dds[d] == 0.f) ? 0.f : (1.f / (float)max(deg[d], 1));
      float4 m;
      m.x = a.x * inv;
      m.y = a.y * inv;
      m.z = a.z * inv;
      m.w = a.w * inv;
      ushort4 hv, lv;
      hv.x = f2b(m.x); lv.x = f2b(m.x - b2f(hv.x));
      hv.y = f2b(m.y); lv.y = f2b(m.y - b2f(hv.y));
      hv.z = f2b(m.z); lv.z = f2b(m.z - b2f(hv.z));
      hv.w = f2b(m.w); lv.w = f2b(m.w - b2f(hv.w));
      const size_t ad = (size_t)(d0 + d) * DD + l * 4;
      *(ushort4*)(mhi + ad) = hv;
      *(ushort4*)(mlo + ad) = lv;
    }
  }
}

// one 64-row MFMA bf16x3 GEMM tile + score epilogue (R8 structure)
__device__ __forceinline__ void gemm_tile(
    SharedMem& sm, const int row0, const unsigned short* __restrict__ Amh,
    const unsigned short* __restrict__ Aml, const float* __restrict__ Ax,
    const float2* __restrict__ tmp, const unsigned short* __restrict__ Whi,
    const unsigned short* __restrict__ Wlo, const float* __restrict__ bias,
    const float* __restrict__ pw, float* __restrict__ outp, float* __restrict__ sraw,
    const int tid) {
  const int wv = tid >> 6;
  const int lane = tid & 63;
  const int q = lane >> 4;
  const int li = lane & 15;

  int sdst[2];
  float ts[2];
#pragma unroll
  for (int i = 0; i < 2; ++i) {
    const int id = tid + i * 256;
    const int r = id >> 3;
    const int kb = (id & 7) << 2;
    sdst[i] = ((r >> 4) * 64 + (kb >> 3) * 16 + (r & 15)) * 8 + (kb & 7);
    ts[i] = tmp[row0 + r].y;
  }

  f32x4 acc[4][2];
#pragma unroll
  for (int m = 0; m < 4; ++m)
#pragma unroll
    for (int n = 0; n < 2; ++n) acc[m][n] = (f32x4){0.f, 0.f, 0.f, 0.f};

  float4 pa[2];
  ushort4 pmh[2], pml[2];
  short8 pbh[2], pbl[2];

#define LOADA(KC)                                                                      \
  {                                                                                    \
    if ((KC) < 4) {                                                                    \
      const int cb = (KC)*32;                                                          \
      _Pragma("unroll") for (int i = 0; i < 2; ++i) {                                  \
        const int id = tid + i * 256;                                                  \
        const size_t ga = (size_t)(row0 + (id >> 3)) * DD + cb + ((id & 7) << 2);      \
        pmh[i] = *(const ushort4*)(Amh + ga);                                          \
        pml[i] = *(const ushort4*)(Aml + ga);                                          \
      }                                                                                \
    } else {                                                                           \
      const int cb = ((KC)&3) * 32;                                                    \
      _Pragma("unroll") for (int i = 0; i < 2; ++i) {                                  \
        const int id = tid + i * 256;                                                  \
        pa[i] = *(const float4*)(Ax + (size_t)(row0 + (id >> 3)) * DD + cb + ((id & 7) << 2)); \
        pa[i].x *= ts[i]; pa[i].y *= ts[i]; pa[i].z *= ts[i]; pa[i].w *= ts[i];        \
      }                                                                                \
    }                                                                                  \
  }
#define LOADB(KC)                                                                      \
  {                                                                                    \
    _Pragma("unroll") for (int n = 0; n < 2; ++n) {                                    \
      const int ga = (((KC)*8 + wv * 2 + n) * 64 + lane) * 8;                          \
      pbh[n] = *(const short8*)(Whi + ga);                                             \
      pbl[n] = *(const short8*)(Wlo + ga);                                             \
    }                                                                                  \
  }

  LOADA(0) LOADB(0)

#pragma unroll
  for (int kc = 0; kc < 8; ++kc) {
    if (kc < 4) {
#pragma unroll
      for (int i = 0; i < 2; ++i) {
        *(ushort4*)(sm.Ah + sdst[i]) = pmh[i];
        *(ushort4*)(sm.Al + sdst[i]) = pml[i];
      }
    } else {
#pragma unroll
      for (int i = 0; i < 2; ++i) {
        ushort4 hv, lv;
        hv.x = f2b(pa[i].x); lv.x = f2b(pa[i].x - b2f(hv.x));
        hv.y = f2b(pa[i].y); lv.y = f2b(pa[i].y - b2f(hv.y));
        hv.z = f2b(pa[i].z); lv.z = f2b(pa[i].z - b2f(hv.z));
        hv.w = f2b(pa[i].w); lv.w = f2b(pa[i].w - b2f(hv.w));
        *(ushort4*)(sm.Ah + sdst[i]) = hv;
        *(ushort4*)(sm.Al + sdst[i]) = lv;
      }
    }
    short8 bh[2], bl[2];
    bh[0] = pbh[0]; bh[1] = pbh[1];
    bl[0] = pbl[0]; bl[1] = pbl[1];
    __syncthreads();
    short8 ah[4], al[4];
#pragma unroll
    for (int m = 0; m < 4; ++m) {
      ah[m] = *(const short8*)(sm.Ah + (m * 64 + lane) * 8);
      al[m] = *(const short8*)(sm.Al + (m * 64 + lane) * 8);
    }
    switch (kc) {
      case 0: LOADA(1) LOADB(1) break;
      case 1: LOADA(2) LOADB(2) break;
      case 2: LOADA(3) LOADB(3) break;
      case 3: LOADA(4) LOADB(4) break;
      case 4: LOADA(5) LOADB(5) break;
      case 5: LOADA(6) LOADB(6) break;
      case 6: LOADA(7) LOADB(7) break;
      default: break;
    }
#pragma unroll
    for (int m = 0; m < 4; ++m)
#pragma unroll
      for (int n = 0; n < 2; ++n) {
        acc[m][n] = __builtin_amdgcn_mfma_f32_16x16x32_bf16(ah[m], bh[n], acc[m][n], 0, 0, 0);
        acc[m][n] = __builtin_amdgcn_mfma_f32_16x16x32_bf16(ah[m], bl[n], acc[m][n], 0, 0, 0);
        acc[m][n] = __builtin_amdgcn_mfma_f32_16x16x32_bf16(al[m], bh[n], acc[m][n], 0, 0, 0);
      }
    __syncthreads();
  }
#undef LOADA
#undef LOADB

  const int c0 = wv * 32 + li;
  const int c1 = wv * 32 + 16 + li;
  const float b0 = bias[c0], b1 = bias[c1];
  const float p0 = pw[c0], p1 = pw[c1];
  float sp[16];
#pragma unroll
  for (int m = 0; m < 4; ++m) {
#pragma unroll
    for (int i = 0; i < 4; ++i) {
      const int r = row0 + m * 16 + q * 4 + i;
      const float v0 = fmaxf(acc[m][0][i] + b0, 0.f);
      const float v1 = fmaxf(acc[m][1][i] + b1, 0.f);
      outp[(size_t)r * DD + c0] = v0;
      outp[(size_t)r * DD + c1] = v1;
      sp[m * 4 + i] = v0 * p0 + v1 * p1;
    }
  }
#pragma unroll
  for (int e = 0; e < 16; ++e) {
    sp[e] += __shfl_xor(sp[e], 1);
    sp[e] += __shfl_xor(sp[e], 2);
    sp[e] += __shfl_xor(sp[e], 4);
    sp[e] += __shfl_xor(sp[e], 8);
  }
  if (li == 0) {
#pragma unroll
    for (int e = 0; e < 16; ++e) sm.s_sp[wv][(e >> 2) * 16 + q * 4 + (e & 3)] = sp[e];
  }
  __syncthreads();
  if (tid < 64)
    sraw[row0 + tid] = sm.s_sp[0][tid] + sm.s_sp[1][tid] + sm.s_sp[2][tid] + sm.s_sp[3][tid];
  __syncthreads();
}

// topk + readout partials for quarter-graph b (R8 pool)
__device__ __forceinline__ void pool_blk(SharedMem& sm, const int b,
                                         const float* __restrict__ h,
                                         const float* __restrict__ sraw,
                                         const float* __restrict__ pw,
                                         const float2* __restrict__ tmP,
                                         float2* __restrict__ tmN, float* __restrict__ zp,
                                         const int kk, const int tid) {
  const int g = b >> 2;
  const int q = b & 3;
  const int lane = tid & 63;

  if (tid < 64) {
    const float v0 = pw[lane], v1 = pw[lane + 64];
    float p = v0 * v0 + v1 * v1;
#pragma unroll
    for (int o = 32; o > 0; o >>= 1) p += __shfl_down(p, o);
    if (lane == 0) sm.s_norm = 1.f / (sqrtf(p) + 1e-16f);
  }
  __syncthreads();
  const float inv_norm = sm.s_norm;
#pragma unroll
  for (int i = 0; i < 2; ++i) {
    const int n = tid + i * 256;
    const int node = g * NPER + n;
    sm.s_sc[n] = (tmP[node].x != 0.f) ? sraw[node] * inv_norm : -INFINITY;
  }
  __syncthreads();

  {
    const int n = q * 128 + (tid & 127);
    const int jb = (tid >> 7) * 256;
    const float s = sm.s_sc[n];
    int rank = 0;
    for (int j = jb; j < jb + 256; ++j) {
      const float sj = sm.s_sc[j];
      rank += (sj > s || (sj == s && j < n)) ? 1 : 0;
    }
    sm.s_rk[tid] = rank;
  }
  __syncthreads();
  if (tid < 128) {
    const int n = q * 128 + tid;
    const int rank = sm.s_rk[tid] + sm.s_rk[tid + 128];
    const int sel = (rank < kk) ? 1 : 0;
    const float s = sm.s_sc[n];
    const float t = sel ? tanhf(s) : 0.f;
    tmN[g * NPER + n] = make_float2(sel ? 1.f : 0.f, t);
    sm.s_sel[tid] = (unsigned char)sel;
    sm.s_t[tid] = t;
  }
  __syncthreads();

  const int c = tid & 31;
  const int r = tid >> 5;
  float4 pmax = make_float4(-INFINITY, -INFINITY, -INFINITY, -INFINITY);
  float4 psum = make_float4(0.f, 0.f, 0.f, 0.f);
  const size_t nbase = (size_t)g * NPER + q * 128;
  const float4* h4 = (const float4*)h;
  for (int i = 0; i < 16; ++i) {
    const int nl = r + 8 * i;
    if (sm.s_sel[nl]) {
      float4 v = h4[(nbase + nl) * 32 + c];
      const float t = sm.s_t[nl];
      v.x *= t; v.y *= t; v.z *= t; v.w *= t;
      pmax.x = fmaxf(pmax.x, v.x);
      pmax.y = fmaxf(pmax.y, v.y);
      pmax.z = fmaxf(pmax.z, v.z);
      pmax.w = fmaxf(pmax.w, v.w);
      psum.x += v.x; psum.y += v.y; psum.z += v.z; psum.w += v.w;
    }
  }
  sm.red4[r * 32 + c] = pmax;
  sm.red4[256 + r * 32 + c] = psum;
  __syncthreads();
  if (tid < 32) {
    float4 m = sm.red4[tid];
    float4 s2 = sm.red4[256 + tid];
#pragma unroll
    for (int rr = 1; rr < 8; ++rr) {
      const float4 a = sm.red4[rr * 32 + tid];
      const float4 s3 = sm.red4[256 + rr * 32 + tid];
      m.x = fmaxf(m.x, a.x); m.y = fmaxf(m.y, a.y);
      m.z = fmaxf(m.z, a.z); m.w = fmaxf(m.w, a.w);
      s2.x += s3.x; s2.y += s3.y; s2.z += s3.z; s2.w += s3.w;
    }
    *(float4*)(zp + (size_t)b * 256 + tid * 4) = m;
    *(float4*)(zp + (size_t)b * 256 + 128 + tid * 4) = s2;
  }
  __syncthreads();
}

__device__ __forceinline__ void mlp_blk(SharedMem& sm, const int g,
                                        const float* __restrict__ zpart,
                                        const float* __restrict__ w1, const float* __restrict__ b1,
                                        const float* __restrict__ w2, const float* __restrict__ b2,
                                        const float* __restrict__ w3, const float* __restrict__ b3,
                                        float* __restrict__ out, const int tid) {
  const float iks[3] = {1.f / 410.f, 1.f / 328.f, 1.f / 263.f};
  if (tid < 128) {
    float zmax = 0.f, zmean = 0.f;
#pragma unroll
    for (int l = 0; l < 3; ++l) {
      const float* zp = zpart + ((size_t)l * 512 + g * 4) * 256;
      zmax += fmaxf(fmaxf(zp[tid], zp[256 + tid]), fmaxf(zp[512 + tid], zp[768 + tid]));
      zmean += (zp[128 + tid] + zp[384 + tid] + zp[640 + tid] + zp[896 + tid]) * iks[l];
    }
    sm.z[tid] = zmax;
    sm.z[128 + tid] = zmean;
  }
  __syncthreads();
  if (tid < 128) {
    float a = b1[tid];
    for (int k = 0; k < 256; ++k) a = fmaf(sm.z[k], w1[tid * 256 + k], a);
    sm.h1[tid] = fmaxf(a, 0.f);
  }
  __syncthreads();
  if (tid < 64) {
    float a2 = b2[tid];
    for (int k = 0; k < 128; ++k) a2 = fmaf(sm.h1[k], w2[tid * 128 + k], a2);
    sm.h2[tid] = fmaxf(a2, 0.f);
  }
  __syncthreads();
  if (tid == 0) {
    float a3 = b3[0];
    for (int k = 0; k < 64; ++k) a3 = fmaf(sm.h2[k], w3[k], a3);
    out[g] = 1.f / (1.f + expf(-a3));
  }
}

// ---------------- mega cooperative kernel ----------------

struct MegaP {
  const float* x; const int* ei;
  const float* wl0; const float* wr0; const float* wl1; const float* wr1;
  const float* wl2; const float* wr2;
  const float* bias0; const float* bias1; const float* bias2;
  const float* pw0; const float* pw1; const float* pw2;
  const float* l1w; const float* l1b; const float* l2w; const float* l2b;
  const float* l3w; const float* l3b;
  int* counts; int* off; int* cursor; float* sraw;
  float2* tmA; float2* tmB; float* zpart;
  unsigned short* Whi; unsigned short* Wlo;
  int* ssrc; unsigned short* mhi; unsigned short* mlo;
  float* hA; float* hB; float* out;
  int* bsum; int* bpre;
};

__global__ __launch_bounds__(256, 2) void mega_kernel(MegaP p) {
  cg::grid_group grid = cg::this_grid();
  __shared__ SharedMem sm;
  const int blk = blockIdx.x;
  const int tid = threadIdx.x;
  const int wv = tid >> 6;
  const int lane = tid & 63;
  const int NT = NBLK * TPB;
  const int gt = blk * TPB + tid;

#define GSYNC()        \
  do {                 \
    __threadfence();   \
    grid.sync();       \
  } while (0)

  // P0: init counts + tm
  for (int i = gt; i < NND; i += NT) {
    p.counts[i] = 0;
    p.tmA[i] = make_float2(1.f, 1.f);
  }
  GSYNC();
  // P1: hist + prepw
  for (int e = gt; e < NED; e += NT) atomicAdd(&p.counts[p.ei[NED + e]], 1);
  for (int e = gt; e < 3 * 32768; e += NT)
    prepw_elem(e, p.wl0, p.wr0, p.wl1, p.wr1, p.wl2, p.wr2, p.Whi, p.Wlo);
  GSYNC();
  // P2: per-block local scan (chunk of 128 counts)
  {
    int c = 0;
    if (tid < 128) {
      c = p.counts[blk * 128 + tid];
      sm.s_tmp[tid] = c;
    }
    __syncthreads();
    for (int d = 1; d < 128; d <<= 1) {
      int v = 0;
      if (tid >= d && tid < 128) v = sm.s_tmp[tid - d];
      __syncthreads();
      if (tid < 128) sm.s_tmp[tid] += v;
      __syncthreads();
    }
    if (tid < 128) sm.s_excl[tid] = sm.s_tmp[tid] - c;
    if (tid == 127) p.bsum[blk] = sm.s_tmp[127];
  }
  GSYNC();
  // P3: block 0 scans the 512 block sums
  if (blk == 0) {
    const int v0 = p.bsum[tid];
    const int v1 = p.bsum[tid + 256];
    sm.s_b[tid] = v0;
    sm.s_b[tid + 256] = v1;
    __syncthreads();
    for (int d = 1; d < 512; d <<= 1) {
      const int a0 = (tid >= d) ? sm.s_b[tid - d] : 0;
      const int a1 = (tid + 256 >= d) ? sm.s_b[tid + 256 - d] : 0;
      __syncthreads();
      sm.s_b[tid] += a0;
      sm.s_b[tid + 256] += a1;
      __syncthreads();
    }
    p.bpre[tid] = sm.s_b[tid] - v0;
    p.bpre[tid + 256] = sm.s_b[tid + 256] - v1;
  }
  GSYNC();
  // P4: write off + cursor
  {
    const int base = p.bpre[blk];
    if (tid < 128) {
      const int v = base + sm.s_excl[tid];
      p.off[blk * 128 + tid] = v;
      p.cursor[blk * 128 + tid] = v;
    }
    if (blk == NBLK - 1 && tid == 255) p.off[NND] = NED;
  }
  GSYNC();
  // P5: scatter
  for (int e = gt; e < NED; e += NT) {
    const int dst = p.ei[NED + e];
    const int pos = atomicAdd(&p.cursor[dst], 1);
    p.ssrc[pos] = p.ei[e];
  }
  GSYNC();

  // layers
  const float* biases[3] = {p.bias0, p.bias1, p.bias2};
  const float* pws[3] = {p.pw0, p.pw1, p.pw2};
  const int ks[3] = {410, 328, 263};
  float* houts[3] = {p.hA, p.hB, p.hA};
  const float2* tps[3] = {p.tmA, p.tmB, p.tmA};
  float2* tns[3] = {p.tmB, p.tmA, p.tmB};
  const float* xl = p.x;
  for (int l = 0; l < 3; ++l) {
    const unsigned short* WhiL = p.Whi + (size_t)l * 32768;
    const unsigned short* WloL = p.Wlo + (size_t)l * 32768;
    float* hout = houts[l];
    // agg: 128 dsts per block
    for (int s = 0; s < 8; ++s)
      agg_group4(blk * 128 + s * 16 + wv * 4, xl, tps[l], p.off, p.ssrc, p.mhi, p.mlo, lane);
    GSYNC();
    // gemm: 2 x 64-row tiles per block (same rows as this block's agg)
    gemm_tile(sm, blk * 128, p.mhi, p.mlo, xl, tps[l], WhiL, WloL, biases[l], pws[l], hout,
              p.sraw, tid);
    gemm_tile(sm, blk * 128 + 64, p.mhi, p.mlo, xl, tps[l], WhiL, WloL, biases[l], pws[l], hout,
              p.sraw, tid);
    GSYNC();
    // pool: block = quarter-graph
    pool_blk(sm, blk, hout, p.sraw, pws[l], tps[l], tns[l],
             p.zpart + (size_t)l * 512 * 256, ks[l], tid);
    GSYNC();
    xl = hout;
  }
  if (blk < NGR)
    mlp_blk(sm, blk, p.zpart, p.l1w, p.l1b, p.l2w, p.l2b, p.l3w, p.l3b, p.out, tid);
#undef GSYNC
}

// ---------------- fallback standalone kernels (R8 structure) ----------------

__global__ __launch_bounds__(256) void init_k(int* counts, float2* tm) {
  int i = blockIdx.x * 256 + threadIdx.x;
  counts[i] = 0;
  tm[i] = make_float2(1.f, 1.f);
}
__global__ __launch_bounds__(256) void hist_k(const int* ei, int* counts) {
  int e = blockIdx.x * 256 + threadIdx.x;
  atomicAdd(&counts[ei[NED + e]], 1);
}
__global__ __launch_bounds__(1024) void scan_k(const int* counts, int* off, int* cursor) {
  __shared__ int part[1024];
  int t = threadIdx.x;
  int base = t * 64;
  int s = 0;
  const int4* c4 = (const int4*)(counts + base);
  for (int i = 0; i < 16; ++i) {
    int4 v = c4[i];
    s += v.x + v.y + v.z + v.w;
  }
  part[t] = s;
  __syncthreads();
  for (int d = 1; d < 1024; d <<= 1) {
    int v = (t >= d) ? part[t - d] : 0;
    __syncthreads();
    part[t] += v;
    __syncthreads();
  }
  int run = (t == 0) ? 0 : part[t - 1];
  for (int i = 0; i < 64; ++i) {
    off[base + i] = run;
    cursor[base + i] = run;
    run += counts[base + i];
  }
  if (t == 1023) off[NND] = NED;
}
__global__ __launch_bounds__(256) void scatter_k(const int* ei, int* cursor, int* ssrc) {
  int e = blockIdx.x * 256 + threadIdx.x;
  int dst = ei[NED + e];
  int pos = atomicAdd(&cursor[dst], 1);
  ssrc[pos] = ei[e];
}
__global__ __launch_bounds__(256) void prepw_k(const float* wl0, const float* wr0,
                                               const float* wl1, const float* wr1,
                                               const float* wl2, const float* wr2,
                                               unsigned short* Whi, unsigned short* Wlo) {
  prepw_elem(blockIdx.x * 256 + threadIdx.x, wl0, wr0, wl1, wr1, wl2, wr2, Whi, Wlo);
}
__global__ __launch_bounds__(256) void agg_k(const float* x, const float2* tm, const int* off,
                                             const int* ssrc, unsigned short* mhi,
                                             unsigned short* mlo) {
  const int wave = threadIdx.x >> 6;
  const int lane = threadIdx.x & 63;
  const int bid = blockIdx.x;
  const int xcd = bid & 7;
  const int slot = bid >> 3;
  const int graph = xcd * 16 + (slot >> 5);
  const int within = slot & 31;
  agg_group4(graph * NPER + within * 16 + wave * 4, x, tm, off, ssrc, mhi, mlo, lane);
}
__global__ __launch_bounds__(256) void gemm_k(const unsigned short* mhi,
                                              const unsigned short* mlo, const float* Ax,
                                              const float2* tmp, const unsigned short* Whi,
                                              const unsigned short* Wlo, const float* bias,
                                              const float* pw, float* outp, float* sraw) {
  __shared__ SharedMem sm;
  gemm_tile(sm, blockIdx.x * 64, mhi, mlo, Ax, tmp, Whi, Wlo, bias, pw, outp, sraw,
            threadIdx.x);
}
__global__ __launch_bounds__(256) void pool_k(const float* h, const float* sraw, const float* pw,
                                              const float2* tmP, float2* tmN, float* zp,
                                              const int kk) {
  __shared__ SharedMem sm;
  pool_blk(sm, blockIdx.x, h, sraw, pw, tmP, tmN, zp, kk, threadIdx.x);
}
__global__ __launch_bounds__(256) void mlp_k(const float* zpart, const float* w1, const float* b1,
                                             const float* w2, const float* b2, const float* w3,
                                             const float* b3, float* out) {
  __shared__ SharedMem sm;
  mlp_blk(sm, blockIdx.x, zpart, w1, b1, w2, b2, w3, b3, out, threadIdx.x);
}

// ---------------- launch ----------------

extern "C" void kernel_launch(void* const* d_in, const int* in_sizes, int n_in,
                              void* d_out, int out_size, void* d_ws, size_t ws_size,
                              hipStream_t stream) {
  (void)in_sizes; (void)n_in; (void)out_size; (void)ws_size;
  const float* x_in = (const float*)d_in[0];
  const int* ei = (const int*)d_in[1];
  const float* wl[3] = {(const float*)d_in[2], (const float*)d_in[6], (const float*)d_in[10]};
  const float* cbl[3] = {(const float*)d_in[3], (const float*)d_in[7], (const float*)d_in[11]};
  const float* wr[3] = {(const float*)d_in[4], (const float*)d_in[8], (const float*)d_in[12]};
  const float* pw[3] = {(const float*)d_in[5], (const float*)d_in[9], (const float*)d_in[13]};

  char* w = (char*)d_ws;
  int* counts = (int*)(w + 0 * (1 << 20));
  int* off = (int*)(w + 1 * (1 << 20));
  int* bsum = (int*)(w + 1 * (1 << 20) + (1 << 19));        // off uses 256KB+4
  int* bpre = (int*)(w + 1 * (1 << 20) + (1 << 19) + 4096);
  int* cursor = (int*)(w + 2 * (1 << 20));
  float* sraw = (float*)(w + 2 * (1 << 20));  // reuses cursor (dead after scatter)
  float2* tmA = (float2*)(w + 3 * (1 << 20));
  float2* tmB = (float2*)(w + 3 * (1 << 20) + (1 << 19));
  float* zpart = (float*)(w + 4 * (1 << 20));  // 1.5MB
  unsigned short* Whi = (unsigned short*)(w + 5 * (1 << 20) + (1 << 19));
  unsigned short* Wlo = (unsigned short*)(w + 5 * (1 << 20) + 3 * (1 << 18));
  int* ssrc = (int*)(w + 6 * (1 << 20));
  unsigned short* mhi = (unsigned short*)(w + (size_t)8 * (1 << 20));
  unsigned short* mlo = (unsigned short*)(w + (size_t)24 * (1 << 20));
  float* hA = (float*)(w + (size_t)40 * (1 << 20));
  float* hB = (float*)(w + (size_t)72 * (1 << 20));

  MegaP p;
  p.x = x_in; p.ei = ei;
  p.wl0 = wl[0]; p.wr0 = wr[0]; p.wl1 = wl[1]; p.wr1 = wr[1]; p.wl2 = wl[2]; p.wr2 = wr[2];
  p.bias0 = cbl[0]; p.bias1 = cbl[1]; p.bias2 = cbl[2];
  p.pw0 = pw[0]; p.pw1 = pw[1]; p.pw2 = pw[2];
  p.l1w = (const float*)d_in[14]; p.l1b = (const float*)d_in[15];
  p.l2w = (const float*)d_in[16]; p.l2b = (const float*)d_in[17];
  p.l3w = (const float*)d_in[18]; p.l3b = (const float*)d_in[19];
  p.counts = counts; p.off = off; p.cursor = cursor; p.sraw = sraw;
  p.tmA = tmA; p.tmB = tmB; p.zpart = zpart;
  p.Whi = Whi; p.Wlo = Wlo; p.ssrc = ssrc; p.mhi = mhi; p.mlo = mlo;
  p.hA = hA; p.hB = hB; p.out = (float*)d_out;
  p.bsum = bsum; p.bpre = bpre;

  void* args[] = {&p};
  hipError_t err = hipLaunchCooperativeKernel((const void*)mega_kernel, dim3(NBLK), dim3(TPB),
                                              args, 0, stream);
  if (err != hipSuccess) {
    (void)hipGetLastError();  // clear; fall back to R8 split sequence
    init_k<<<NND / 256, 256, 0, stream>>>(counts, tmA);
    hist_k<<<NED / 256, 256, 0, stream>>>(ei, counts);
    scan_k<<<1, 1024, 0, stream>>>(counts, off, cursor);
    scatter_k<<<NED / 256, 256, 0, stream>>>(ei, cursor, ssrc);
    prepw_k<<<384, 256, 0, stream>>>(wl[0], wr[0], wl[1], wr[1], wl[2], wr[2], Whi, Wlo);
    const int ks[3] = {410, 328, 263};
    const float* xl = x_in;
    float* houts[3] = {hA, hB, hA};
    float2* tprev[3] = {tmA, tmB, tmA};
    float2* tnext[3] = {tmB, tmA, tmB};
    for (int l = 0; l < 3; ++l) {
      float* hout = houts[l];
      agg_k<<<4096, 256, 0, stream>>>(xl, tprev[l], off, ssrc, mhi, mlo);
      gemm_k<<<1024, 256, 0, stream>>>(mhi, mlo, xl, tprev[l], Whi + (size_t)l * 32768,
                                       Wlo + (size_t)l * 32768, cbl[l], pw[l], hout, sraw);
      pool_k<<<512, 256, 0, stream>>>(hout, sraw, pw[l], tprev[l], tnext[l],
                                      zpart + (size_t)l * 512 * 256, ks[l]);
      xl = hout;
    }
    mlp_k<<<NGR, 128, 0, stream>>>(zpart, p.l1w, p.l1b, p.l2w, p.l2b, p.l3w, p.l3b,
                                   (float*)d_out);
  }
}

// Round 11
// 425.182 us; speedup vs baseline: 4.7593x; 4.7593x over previous
//
#include <hip/hip_runtime.h>
#include <math.h>

#define NND 65536   // total nodes
#define NPER 512    // nodes per graph
#define NGR 128     // graphs (B)
#define DD 128      // feature dim
#define NED 524288  // edges

typedef __attribute__((ext_vector_type(8))) short short8;
typedef __attribute__((ext_vector_type(4))) float f32x4;

__device__ __forceinline__ unsigned short f2b(float f) {
  unsigned u = __float_as_uint(f);
  return (unsigned short)((u + 0x7FFFu + ((u >> 16) & 1u)) >> 16);
}
__device__ __forceinline__ float b2f(unsigned short h) {
  return __uint_as_float(((unsigned)h) << 16);
}

// ---------------- setup: counts=0, tm={1,1}, weight prep (fused) ----------------
// prepw layout: Whi[l][kc][nt][lane][j] (MFMA fragment order), l=0..2.

__global__ __launch_bounds__(256) void setup_kernel(
    int* __restrict__ counts, float2* __restrict__ tm,
    const float* __restrict__ wl0, const float* __restrict__ wr0,
    const float* __restrict__ wl1, const float* __restrict__ wr1,
    const float* __restrict__ wl2, const float* __restrict__ wr2,
    unsigned short* __restrict__ Whi, unsigned short* __restrict__ Wlo) {
  const int e = blockIdx.x * 256 + threadIdx.x;  // 384*256 = 98304
  if (e < NND) {
    counts[e] = 0;
    tm[e] = make_float2(1.f, 1.f);
  }
  const float* wls[3] = {wl0, wl1, wl2};
  const float* wrs[3] = {wr0, wr1, wr2};
  int l = e >> 15;
  int o = e & 32767;
  int j = o & 7;
  int lane = (o >> 3) & 63;
  int nt = (o >> 9) & 7;
  int kc = o >> 12;
  int li = lane & 15, q = lane >> 4;
  int n = nt * 16 + li;
  int k = kc * 32 + q * 8 + j;
  const float* src = (k < 128) ? wls[l] : wrs[l];
  float v = src[n * DD + (k & 127)];
  unsigned short hi = f2b(v);
  Whi[e] = hi;
  Wlo[e] = f2b(v - b2f(hi));
}

__global__ __launch_bounds__(256) void hist_kernel(const int* __restrict__ ei,
                                                   int* __restrict__ counts) {
  int e = blockIdx.x * 256 + threadIdx.x;
  atomicAdd(&counts[ei[NED + e]], 1);
}

__global__ __launch_bounds__(1024) void scan_kernel(const int* __restrict__ counts,
                                                    int* __restrict__ off,
                                                    int* __restrict__ cursor) {
  __shared__ int part[1024];
  int t = threadIdx.x;
  int base = t * 64;
  int s = 0;
  const int4* c4 = (const int4*)(counts + base);
  for (int i = 0; i < 16; ++i) {
    int4 v = c4[i];
    s += v.x + v.y + v.z + v.w;
  }
  part[t] = s;
  __syncthreads();
  for (int d = 1; d < 1024; d <<= 1) {
    int v = (t >= d) ? part[t - d] : 0;
    __syncthreads();
    part[t] += v;
    __syncthreads();
  }
  int run = (t == 0) ? 0 : part[t - 1];
  for (int i = 0; i < 64; ++i) {
    off[base + i] = run;
    cursor[base + i] = run;
    run += counts[base + i];
  }
  if (t == 1023) off[NND] = NED;
}

__global__ __launch_bounds__(256) void scatter_kernel(const int* __restrict__ ei,
                                                      int* __restrict__ cursor,
                                                      int* __restrict__ ssrc) {
  int e = blockIdx.x * 256 + threadIdx.x;
  int dst = ei[NED + e];
  int pos = atomicAdd(&cursor[dst], 1);
  ssrc[pos] = ei[e];
}

// ---------------- agg device body: 4 consecutive dsts per wave ----------------
// Writes bf16 hi/lo mean rows to global (mhi/mlo). FIRST=1 skips tm gathers.

template <int FIRST>
__device__ __forceinline__ void agg_group4(const int d0, const float* __restrict__ x,
                                           const float2* __restrict__ tm,
                                           const int* __restrict__ off,
                                           const int* __restrict__ ssrc,
                                           unsigned short* __restrict__ mhi,
                                           unsigned short* __restrict__ mlo,
                                           const int lane) {
  const int half = lane >> 5;
  const int l = lane & 31;
  int offv = 0;
  if (lane < 5) offv = off[d0 + lane];
  float deadv = 1.f;
  if (!FIRST && lane < 4) deadv = tm[d0 + lane].x;
  const int b0 = __shfl(offv, 0);
  const int b1 = __shfl(offv, 1);
  const int b2 = __shfl(offv, 2);
  const int b3 = __shfl(offv, 3);
  const int e3 = __shfl(offv, 4);
  float dds[4] = {1.f, 1.f, 1.f, 1.f};
  if (!FIRST) {
    dds[0] = __shfl(deadv, 0);
    dds[1] = __shfl(deadv, 1);
    dds[2] = __shfl(deadv, 2);
    dds[3] = __shfl(deadv, 3);
  }
  const int begs[4] = {b0, b1, b2, b3};
  const int ends[4] = {b1, b2, b3, e3};

  float4 acc[4];
  int deg[4];
#pragma unroll
  for (int d = 0; d < 4; ++d) {
    acc[d] = make_float4(0.f, 0.f, 0.f, 0.f);
    deg[d] = 0;
  }

  for (int base = b0; base < e3; base += 64) {
    const int nwin = min(64, e3 - base);
    int sv = 0;
    float tv = 0.f;
    int live = 0;
    if (lane < nwin) {
      sv = ssrc[base + lane];
      if (!FIRST) {
        const float2 mt = tm[sv];
        live = (mt.x != 0.f);
        tv = mt.y;
      }
    }
    unsigned long long bl;
    if (!FIRST)
      bl = __ballot(live);
    else
      bl = (nwin == 64) ? ~0ull : ((1ull << nwin) - 1);

#pragma unroll
    for (int d = 0; d < 4; ++d) {
      if (!FIRST && dds[d] == 0.f) continue;
      const int lo = max(begs[d], base);
      const int hi = min(ends[d], base + 64);
      if (lo >= hi) continue;
      const int j0 = lo - base;
      const int j1 = hi - base;
      const unsigned long long wm =
          (((j1 == 64) ? ~0ull : ((1ull << j1) - 1)) & ~((1ull << j0) - 1));
      deg[d] += (int)__popcll(bl & wm);
      int j = j0 + half;
      for (; j + 6 < j1; j += 8) {  // 4 edges per 32-lane half in flight
        const int s0 = __shfl(sv, j);
        const int s1 = __shfl(sv, j + 2);
        const int s2 = __shfl(sv, j + 4);
        const int s3 = __shfl(sv, j + 6);
        const float4 v0 = *(const float4*)(x + (size_t)s0 * DD + l * 4);
        const float4 v1 = *(const float4*)(x + (size_t)s1 * DD + l * 4);
        const float4 v2 = *(const float4*)(x + (size_t)s2 * DD + l * 4);
        const float4 v3 = *(const float4*)(x + (size_t)s3 * DD + l * 4);
        if (!FIRST) {
          const float t0 = __shfl(tv, j), t1 = __shfl(tv, j + 2);
          const float t2 = __shfl(tv, j + 4), t3 = __shfl(tv, j + 6);
          acc[d].x += v0.x * t0 + v1.x * t1 + v2.x * t2 + v3.x * t3;
          acc[d].y += v0.y * t0 + v1.y * t1 + v2.y * t2 + v3.y * t3;
          acc[d].z += v0.z * t0 + v1.z * t1 + v2.z * t2 + v3.z * t3;
          acc[d].w += v0.w * t0 + v1.w * t1 + v2.w * t2 + v3.w * t3;
        } else {
          acc[d].x += v0.x + v1.x + v2.x + v3.x;
          acc[d].y += v0.y + v1.y + v2.y + v3.y;
          acc[d].z += v0.z + v1.z + v2.z + v3.z;
          acc[d].w += v0.w + v1.w + v2.w + v3.w;
        }
      }
      for (; j < j1; j += 2) {
        const int s = __shfl(sv, j);
        const float4 v = *(const float4*)(x + (size_t)s * DD + l * 4);
        if (!FIRST) {
          const float t = __shfl(tv, j);
          acc[d].x += v.x * t;
          acc[d].y += v.y * t;
          acc[d].z += v.z * t;
          acc[d].w += v.w * t;
        } else {
          acc[d].x += v.x;
          acc[d].y += v.y;
          acc[d].z += v.z;
          acc[d].w += v.w;
        }
      }
    }
  }

#pragma unroll
  for (int d = 0; d < 4; ++d) {
    float4 a = acc[d];
    a.x += __shfl(a.x, lane ^ 32);
    a.y += __shfl(a.y, lane ^ 32);
    a.z += __shfl(a.z, lane ^ 32);
    a.w += __shfl(a.w, lane ^ 32);
    if (lane < 32) {
      const float inv = (!FIRST && dds[d] == 0.f) ? 0.f : (1.f / (float)max(deg[d], 1));
      float4 m;
      m.x = a.x * inv;
      m.y = a.y * inv;
      m.z = a.z * inv;
      m.w = a.w * inv;
      ushort4 hv, lv;
      hv.x = f2b(m.x); lv.x = f2b(m.x - b2f(hv.x));
      hv.y = f2b(m.y); lv.y = f2b(m.y - b2f(hv.y));
      hv.z = f2b(m.z); lv.z = f2b(m.z - b2f(hv.z));
      hv.w = f2b(m.w); lv.w = f2b(m.w - b2f(hv.w));
      const size_t ad = (size_t)(d0 + d) * DD + l * 4;
      *(ushort4*)(mhi + ad) = hv;
      *(ushort4*)(mlo + ad) = lv;
    }
  }
}

// ---------------- FUSED agg + MFMA bf16x3 GEMM + score per 64-row block -------
// Phase A: block aggregates its own 64 rows -> global mhi/mlo (bf16 hi/lo).
//   L2-resident round trip; LDS stays 9.25KB so occupancy is not LDS-limited
//   (R9 lesson: 43KB smean -> 3 blocks/CU killed the gather phase).
// Phase B (after __syncthreads, which orders global writes within the block):
//   h = relu([mean | t.*x] @ W + bl) via fragment-ordered MFMA (R8-proven),
//   score epilogue -> sraw. Blocks finishing A early start MFMA while others
//   gather -> cross-block pipe overlap (m114) without grid sync.

#define GBM 64

struct GemmSmem {
  short Ah[2048];
  short Al[2048];
  float s_sp[4][GBM];
};  // 9.25 KB

template <int FIRST>
__global__ __launch_bounds__(256) void aggemm_kernel_t(
    const float* __restrict__ x, const float2* __restrict__ tm,
    const int* __restrict__ off, const int* __restrict__ ssrc,
    unsigned short* __restrict__ mhi, unsigned short* __restrict__ mlo,
    const unsigned short* __restrict__ Whi, const unsigned short* __restrict__ Wlo,
    const float* __restrict__ bias, const float* __restrict__ pw,
    float* __restrict__ outp, float* __restrict__ sraw) {
  __shared__ GemmSmem sm;
  const int tid = threadIdx.x;
  const int wv = tid >> 6;
  const int lane = tid & 63;
  const int q = lane >> 4;
  const int li = lane & 15;
  // 1024 blocks = 8 xcd * 16 graphs * 8 tiles (graph locality per XCD)
  const int bid = blockIdx.x;
  const int xcd = bid & 7;
  const int slot = bid >> 3;
  const int graph = xcd * 16 + (slot >> 3);
  const int mtile = slot & 7;
  const int row0 = graph * NPER + mtile * GBM;

  // Phase A: 16 groups of 4 dsts; wave wv takes groups {wv, wv+4, wv+8, wv+12}
#pragma unroll
  for (int s = 0; s < 4; ++s)
    agg_group4<FIRST>(row0 + (s * 4 + wv) * 4, x, tm, off, ssrc, mhi, mlo, lane);
  __syncthreads();  // block's mhi/mlo writes visible to all its waves

  // Phase B: GEMM on this block's 64 rows
  int sdst[2];
  float ts[2];
#pragma unroll
  for (int i = 0; i < 2; ++i) {
    const int id = tid + i * 256;
    const int r = id >> 3;
    const int kb = (id & 7) << 2;
    sdst[i] = ((r >> 4) * 64 + (kb >> 3) * 16 + (r & 15)) * 8 + (kb & 7);
    ts[i] = FIRST ? 1.f : tm[row0 + r].y;
  }

  f32x4 acc[4][2];
#pragma unroll
  for (int m = 0; m < 4; ++m)
#pragma unroll
    for (int n = 0; n < 2; ++n) acc[m][n] = (f32x4){0.f, 0.f, 0.f, 0.f};

  float4 pa[2];
  ushort4 pmh[2], pml[2];
  short8 pbh[2], pbl[2];

#define LOADA(KC)                                                                      \
  {                                                                                    \
    if ((KC) < 4) {                                                                    \
      const int cb = (KC)*32;                                                          \
      _Pragma("unroll") for (int i = 0; i < 2; ++i) {                                  \
        const int id = tid + i * 256;                                                  \
        const size_t ga = (size_t)(row0 + (id >> 3)) * DD + cb + ((id & 7) << 2);      \
        pmh[i] = *(const ushort4*)(mhi + ga);                                          \
        pml[i] = *(const ushort4*)(mlo + ga);                                          \
      }                                                                                \
    } else {                                                                           \
      const int cb = ((KC)&3) * 32;                                                    \
      _Pragma("unroll") for (int i = 0; i < 2; ++i) {                                  \
        const int id = tid + i * 256;                                                  \
        pa[i] = *(const float4*)(x + (size_t)(row0 + (id >> 3)) * DD + cb + ((id & 7) << 2)); \
        if (!FIRST) {                                                                  \
          pa[i].x *= ts[i]; pa[i].y *= ts[i]; pa[i].z *= ts[i]; pa[i].w *= ts[i];      \
        }                                                                              \
      }                                                                                \
    }                                                                                  \
  }
#define LOADB(KC)                                                                      \
  {                                                                                    \
    _Pragma("unroll") for (int n = 0; n < 2; ++n) {                                    \
      const int ga = (((KC)*8 + wv * 2 + n) * 64 + lane) * 8;                          \
      pbh[n] = *(const short8*)(Whi + ga);                                             \
      pbl[n] = *(const short8*)(Wlo + ga);                                             \
    }                                                                                  \
  }

  LOADA(0) LOADB(0)

#pragma unroll
  for (int kc = 0; kc < 8; ++kc) {
    if (kc < 4) {
#pragma unroll
      for (int i = 0; i < 2; ++i) {
        *(ushort4*)(sm.Ah + sdst[i]) = pmh[i];
        *(ushort4*)(sm.Al + sdst[i]) = pml[i];
      }
    } else {
#pragma unroll
      for (int i = 0; i < 2; ++i) {
        ushort4 hv, lv;
        hv.x = f2b(pa[i].x); lv.x = f2b(pa[i].x - b2f(hv.x));
        hv.y = f2b(pa[i].y); lv.y = f2b(pa[i].y - b2f(hv.y));
        hv.z = f2b(pa[i].z); lv.z = f2b(pa[i].z - b2f(hv.z));
        hv.w = f2b(pa[i].w); lv.w = f2b(pa[i].w - b2f(hv.w));
        *(ushort4*)(sm.Ah + sdst[i]) = hv;
        *(ushort4*)(sm.Al + sdst[i]) = lv;
      }
    }
    short8 bh[2], bl[2];
    bh[0] = pbh[0]; bh[1] = pbh[1];
    bl[0] = pbl[0]; bl[1] = pbl[1];
    __syncthreads();
    short8 ah[4], al[4];
#pragma unroll
    for (int m = 0; m < 4; ++m) {
      ah[m] = *(const short8*)(sm.Ah + (m * 64 + lane) * 8);
      al[m] = *(const short8*)(sm.Al + (m * 64 + lane) * 8);
    }
    switch (kc) {  // prefetch next chunk; overlaps MFMA below
      case 0: LOADA(1) LOADB(1) break;
      case 1: LOADA(2) LOADB(2) break;
      case 2: LOADA(3) LOADB(3) break;
      case 3: LOADA(4) LOADB(4) break;
      case 4: LOADA(5) LOADB(5) break;
      case 5: LOADA(6) LOADB(6) break;
      case 6: LOADA(7) LOADB(7) break;
      default: break;
    }
#pragma unroll
    for (int m = 0; m < 4; ++m)
#pragma unroll
      for (int n = 0; n < 2; ++n) {
        acc[m][n] = __builtin_amdgcn_mfma_f32_16x16x32_bf16(ah[m], bh[n], acc[m][n], 0, 0, 0);
        acc[m][n] = __builtin_amdgcn_mfma_f32_16x16x32_bf16(ah[m], bl[n], acc[m][n], 0, 0, 0);
        acc[m][n] = __builtin_amdgcn_mfma_f32_16x16x32_bf16(al[m], bh[n], acc[m][n], 0, 0, 0);
      }
    __syncthreads();
  }
#undef LOADA
#undef LOADB

  // epilogue: bias+relu, store h (unscaled), fused score partials
  const int c0 = wv * 32 + li;
  const int c1 = wv * 32 + 16 + li;
  const float b0 = bias[c0], b1 = bias[c1];
  const float p0 = pw[c0], p1 = pw[c1];
  float sp[16];
#pragma unroll
  for (int m = 0; m < 4; ++m) {
#pragma unroll
    for (int i = 0; i < 4; ++i) {
      const int r = row0 + m * 16 + q * 4 + i;
      const float v0 = fmaxf(acc[m][0][i] + b0, 0.f);
      const float v1 = fmaxf(acc[m][1][i] + b1, 0.f);
      outp[(size_t)r * DD + c0] = v0;
      outp[(size_t)r * DD + c1] = v1;
      sp[m * 4 + i] = v0 * p0 + v1 * p1;
    }
  }
#pragma unroll
  for (int e = 0; e < 16; ++e) {
    sp[e] += __shfl_xor(sp[e], 1);
    sp[e] += __shfl_xor(sp[e], 2);
    sp[e] += __shfl_xor(sp[e], 4);
    sp[e] += __shfl_xor(sp[e], 8);
  }
  if (li == 0) {
#pragma unroll
    for (int e = 0; e < 16; ++e) sm.s_sp[wv][(e >> 2) * 16 + q * 4 + (e & 3)] = sp[e];
  }
  __syncthreads();
  if (tid < GBM)
    sraw[row0 + tid] = sm.s_sp[0][tid] + sm.s_sp[1][tid] + sm.s_sp[2][tid] + sm.s_sp[3][tid];
}

// ---------------- topk + readout partials (R8, h read-only) ----------------

__global__ __launch_bounds__(256) void pool_kernel(const float* __restrict__ h,
                                                   const float* __restrict__ sraw,
                                                   const float* __restrict__ pw,
                                                   const float2* __restrict__ tmP,
                                                   float2* __restrict__ tmN,
                                                   float* __restrict__ zp,
                                                   const int kk) {
  __shared__ float s_sc[NPER];
  __shared__ float s_t[128];
  __shared__ unsigned char s_sel[128];
  __shared__ int s_rk[256];
  __shared__ float4 red4[512];
  __shared__ float s_norm;
  const int b = blockIdx.x;
  const int g = b >> 2;
  const int q = b & 3;
  const int tid = threadIdx.x;
  const int lane = tid & 63;

  if (tid < 64) {
    const float v0 = pw[lane], v1 = pw[lane + 64];
    float p = v0 * v0 + v1 * v1;
#pragma unroll
    for (int o = 32; o > 0; o >>= 1) p += __shfl_down(p, o);
    if (lane == 0) s_norm = 1.f / (sqrtf(p) + 1e-16f);
  }
  __syncthreads();
  const float inv_norm = s_norm;
#pragma unroll
  for (int i = 0; i < 2; ++i) {
    const int n = tid + i * 256;
    const int node = g * NPER + n;
    s_sc[n] = (tmP[node].x != 0.f) ? sraw[node] * inv_norm : -INFINITY;
  }
  __syncthreads();

  {
    const int n = q * 128 + (tid & 127);
    const int jb = (tid >> 7) * 256;
    const float s = s_sc[n];
    int rank = 0;
    for (int j = jb; j < jb + 256; ++j) {
      const float sj = s_sc[j];
      rank += (sj > s || (sj == s && j < n)) ? 1 : 0;
    }
    s_rk[tid] = rank;
  }
  __syncthreads();
  if (tid < 128) {
    const int n = q * 128 + tid;
    const int rank = s_rk[tid] + s_rk[tid + 128];
    const int sel = (rank < kk) ? 1 : 0;
    const float s = s_sc[n];
    const float t = sel ? tanhf(s) : 0.f;
    tmN[g * NPER + n] = make_float2(sel ? 1.f : 0.f, t);
    s_sel[tid] = (unsigned char)sel;
    s_t[tid] = t;
  }
  __syncthreads();

  const int c = tid & 31;
  const int r = tid >> 5;
  float4 pmax = make_float4(-INFINITY, -INFINITY, -INFINITY, -INFINITY);
  float4 psum = make_float4(0.f, 0.f, 0.f, 0.f);
  const size_t nbase = (size_t)g * NPER + q * 128;
  const float4* h4 = (const float4*)h;
  for (int i = 0; i < 16; ++i) {
    const int nl = r + 8 * i;
    if (s_sel[nl]) {
      float4 v = h4[(nbase + nl) * 32 + c];
      const float t = s_t[nl];
      v.x *= t; v.y *= t; v.z *= t; v.w *= t;
      pmax.x = fmaxf(pmax.x, v.x);
      pmax.y = fmaxf(pmax.y, v.y);
      pmax.z = fmaxf(pmax.z, v.z);
      pmax.w = fmaxf(pmax.w, v.w);
      psum.x += v.x; psum.y += v.y; psum.z += v.z; psum.w += v.w;
    }
  }
  red4[r * 32 + c] = pmax;
  red4[256 + r * 32 + c] = psum;
  __syncthreads();
  if (tid < 32) {
    float4 m = red4[tid];
    float4 sm2 = red4[256 + tid];
#pragma unroll
    for (int rr = 1; rr < 8; ++rr) {
      const float4 a = red4[rr * 32 + tid];
      const float4 s3 = red4[256 + rr * 32 + tid];
      m.x = fmaxf(m.x, a.x); m.y = fmaxf(m.y, a.y);
      m.z = fmaxf(m.z, a.z); m.w = fmaxf(m.w, a.w);
      sm2.x += s3.x; sm2.y += s3.y; sm2.z += s3.z; sm2.w += s3.w;
    }
    *(float4*)(zp + (size_t)b * 256 + tid * 4) = m;
    *(float4*)(zp + (size_t)b * 256 + 128 + tid * 4) = sm2;
  }
}

// ---------------- MLP head (reduces 4 partials/graph/layer) ----------------

__global__ __launch_bounds__(128) void mlp_kernel(const float* __restrict__ zpart,
                                                  const float* __restrict__ w1,
                                                  const float* __restrict__ b1,
                                                  const float* __restrict__ w2,
                                                  const float* __restrict__ b2,
                                                  const float* __restrict__ w3,
                                                  const float* __restrict__ b3,
                                                  float* __restrict__ out) {
  __shared__ float z[256];
  __shared__ float h1[128];
  __shared__ float h2[64];
  const int g = blockIdx.x;
  const int t = threadIdx.x;
  const float iks[3] = {1.f / 410.f, 1.f / 328.f, 1.f / 263.f};
  float zmax = 0.f, zmean = 0.f;
#pragma unroll
  for (int l = 0; l < 3; ++l) {
    const float* zp = zpart + ((size_t)l * 512 + g * 4) * 256;
    zmax += fmaxf(fmaxf(zp[t], zp[256 + t]), fmaxf(zp[512 + t], zp[768 + t]));
    zmean += (zp[128 + t] + zp[384 + t] + zp[640 + t] + zp[896 + t]) * iks[l];
  }
  z[t] = zmax;
  z[128 + t] = zmean;
  __syncthreads();
  float a = b1[t];
  for (int k = 0; k < 256; ++k) a = fmaf(z[k], w1[t * 256 + k], a);
  h1[t] = fmaxf(a, 0.f);
  __syncthreads();
  if (t < 64) {
    float a2 = b2[t];
    for (int k = 0; k < 128; ++k) a2 = fmaf(h1[k], w2[t * 128 + k], a2);
    h2[t] = fmaxf(a2, 0.f);
  }
  __syncthreads();
  if (t == 0) {
    float a3 = b3[0];
    for (int k = 0; k < 64; ++k) a3 = fmaf(h2[k], w3[k], a3);
    out[g] = 1.f / (1.f + expf(-a3));
  }
}

// ---------------- launch ----------------

extern "C" void kernel_launch(void* const* d_in, const int* in_sizes, int n_in,
                              void* d_out, int out_size, void* d_ws, size_t ws_size,
                              hipStream_t stream) {
  (void)in_sizes; (void)n_in; (void)out_size; (void)ws_size;
  const float* x_in = (const float*)d_in[0];
  const int* ei = (const int*)d_in[1];
  const float* wl[3] = {(const float*)d_in[2], (const float*)d_in[6], (const float*)d_in[10]};
  const float* cbl[3] = {(const float*)d_in[3], (const float*)d_in[7], (const float*)d_in[11]};
  const float* wr[3] = {(const float*)d_in[4], (const float*)d_in[8], (const float*)d_in[12]};
  const float* pw[3] = {(const float*)d_in[5], (const float*)d_in[9], (const float*)d_in[13]};
  const float* l1w = (const float*)d_in[14];
  const float* l1b = (const float*)d_in[15];
  const float* l2w = (const float*)d_in[16];
  const float* l2b = (const float*)d_in[17];
  const float* l3w = (const float*)d_in[18];
  const float* l3b = (const float*)d_in[19];
  float* out = (float*)d_out;

  char* w = (char*)d_ws;
  int* counts = (int*)(w + 0 * (1 << 20));    // dead after scan
  int* off = (int*)(w + 1 * (1 << 20));
  int* cursor = (int*)(w + 2 * (1 << 20));    // dead after scatter
  float* sraw = (float*)(w + 2 * (1 << 20));  // reuses cursor (256KB)
  float2* tmA = (float2*)(w + 3 * (1 << 20));              // 512KB
  float2* tmB = (float2*)(w + 3 * (1 << 20) + (1 << 19));  // 512KB
  float* zpart = (float*)(w + 4 * (1 << 20));              // 1.5MB
  unsigned short* Whi = (unsigned short*)(w + 5 * (1 << 20) + (1 << 19));      // 192KB
  unsigned short* Wlo = (unsigned short*)(w + 5 * (1 << 20) + 3 * (1 << 18));  // 192KB
  int* ssrc = (int*)(w + 6 * (1 << 20));                                 // 2MB
  unsigned short* mhi = (unsigned short*)(w + (size_t)8 * (1 << 20));    // 16MB
  unsigned short* mlo = (unsigned short*)(w + (size_t)24 * (1 << 20));   // 16MB
  float* hA = (float*)(w + (size_t)40 * (1 << 20));  // 32MB
  float* hB = (float*)(w + (size_t)72 * (1 << 20));  // 32MB (total 104MB)

  setup_kernel<<<384, 256, 0, stream>>>(counts, tmA, wl[0], wr[0], wl[1], wr[1], wl[2], wr[2],
                                        Whi, Wlo);
  hist_kernel<<<NED / 256, 256, 0, stream>>>(ei, counts);
  scan_kernel<<<1, 1024, 0, stream>>>(counts, off, cursor);
  scatter_kernel<<<NED / 256, 256, 0, stream>>>(ei, cursor, ssrc);

  const int ks[3] = {410, 328, 263};
  const float* xl = x_in;
  float* houts[3] = {hA, hB, hA};
  float2* tprev[3] = {tmA, tmB, tmA};
  float2* tnext[3] = {tmB, tmA, tmB};
  for (int l = 0; l < 3; ++l) {
    float* hout = houts[l];
    if (l == 0)
      aggemm_kernel_t<1><<<1024, 256, 0, stream>>>(xl, tprev[l], off, ssrc, mhi, mlo,
                                                   Whi + (size_t)l * 32768,
                                                   Wlo + (size_t)l * 32768, cbl[l], pw[l],
                                                   hout, sraw);
    else
      aggemm_kernel_t<0><<<1024, 256, 0, stream>>>(xl, tprev[l], off, ssrc, mhi, mlo,
                                                   Whi + (size_t)l * 32768,
                                                   Wlo + (size_t)l * 32768, cbl[l], pw[l],
                                                   hout, sraw);
    pool_kernel<<<NGR * 4, 256, 0, stream>>>(hout, sraw, pw[l], tprev[l], tnext[l],
                                             zpart + (size_t)l * 512 * 256, ks[l]);
    xl = hout;
  }
  mlp_kernel<<<NGR, 128, 0, stream>>>(zpart, l1w, l1b, l2w, l2b, l3w, l3b, out);
}